// Round 7
// baseline (49.715 us; speedup 1.0000x reference)
//
#include <hip/hip_runtime.h>

// ROI max-pool (aspect-preserving "OCR" variant) — separable two-phase, v4.
// feats: (B=4, C=128, H=64, W=512) fp32
// rois:  (N=256, 5) fp32 = [batch, x1, y1, x2, y2], spatial scale 0.25
// out:   (N, C, PH=8, PW=32) fp32
//
// Kernel 1 (roi_prep): per-ROI bin geometry -> d_ws (exact reference math).
// Kernel 2 (pool): block = (roi, ph, channel-half of 64); 32 w-lanes x 8
// cslots, cslot covers 8 channels (stride 8) -> 16 dwordx4 in flight/thread.
// Phase 1: rowmax over h -> LDS (float4). Phase 2: w-max from LDS.
// Block index XCD-swizzled so one ROI's 16 blocks share one XCD's L2.

#define PHB 8
#define PWB 32
#define CHB 64
#define WST 116         // >= max staged width (<=111)
#define BLK 256

static __device__ __forceinline__ float4 max4(float4 a, float4 b) {
    float4 r;
    r.x = fmaxf(a.x, b.x); r.y = fmaxf(a.y, b.y);
    r.z = fmaxf(a.z, b.z); r.w = fmaxf(a.w, b.w);
    return r;
}

// d_ws layout: A: int4[nroi] @0 ; Bh: int[nroi*8] @4096 ; Cw: int[nroi*32] @12288
__global__ void roi_prep(const float* __restrict__ rois, int nroi,
                         int4* __restrict__ A, int* __restrict__ Bh,
                         int* __restrict__ Cw, int Hc, int Wc)
{
#pragma clang fp contract(off)
    int i = blockIdx.x * 64 + threadIdx.x;
    if (i >= nroi) return;
    const float* r = rois + i * 5;
    int rb  = (int)r[0];
    int rsw = (int)floorf(r[1] * 0.25f + 0.5f);
    int rsh = (int)floorf(r[2] * 0.25f + 0.5f);
    int rew = (int)floorf(r[3] * 0.25f + 0.5f);
    int reh = (int)floorf(r[4] * 0.25f + 0.5f);

    int roi_w = max(rew - rsw + 1, 1);
    int roi_h = max(reh - rsh + 1, 1);
    int rpw   = (PHB * roi_w + roi_h - 1) / roi_h;

    float bsh = (float)roi_h / (float)PHB;
    float bsw = (float)roi_w / (float)rpw;

    // staged window (4-aligned); covers every non-pad bin's [ws,we)
    int wlo = min(max(rsw, 0), Wc);
    int whi = (int)ceilf((float)PWB * bsw) + rsw;
    whi = min(whi, rew + 4);
    whi = min(max(whi, 0), Wc);
    int wlo_al = wlo & ~3;
    int wwid   = min(whi - wlo_al, WST);

    A[i] = make_int4(rb, wlo_al, wwid, 0);

#pragma unroll
    for (int ph = 0; ph < PHB; ++ph) {
        int hs = (int)floorf((float)ph * bsh) + rsh;
        int he = (int)ceilf((float)(ph + 1) * bsh) + rsh;
        hs = min(max(hs, 0), Hc);
        he = min(max(he, 0), Hc);
        Bh[i * PHB + ph] = hs | (he << 16);
    }
#pragma unroll
    for (int pw = 0; pw < PWB; ++pw) {
        int ws = (int)floorf((float)pw * bsw) + rsw;
        int we = (int)ceilf((float)(pw + 1) * bsw) + rsw;
        ws = min(max(ws, 0), Wc);
        we = min(max(we, 0), Wc);
        int zw = (ws >= rew) || (we <= ws);   // pad or empty-in-w
        Cw[i * PWB + pw] = ws | (zw << 15) | (we << 16);
    }
}

__global__ __launch_bounds__(BLK) void ocr_roi_pool_kernel(
    const float* __restrict__ feats,
    const int4* __restrict__ A,
    const int* __restrict__ Bh,
    const int* __restrict__ Cw,
    float* __restrict__ out,
    int Cc, int Hc, int Wc)
{
    __shared__ float smax[CHB * WST];

    // XCD-swizzled decode: one ROI's 16 blocks -> same XCD (bid % 8)
    int bid = blockIdx.x;
    int n   = (bid & 7) + 8 * (bid >> 7);
    int s   = (bid >> 3) & 15;
    int ph  = s >> 1;
    int cq  = s & 1;
    int c0  = cq * CHB;

    int4 a      = A[n];
    int  rb     = a.x;
    int  wlo_al = a.y;
    int  wwid   = a.z;
    int  hh     = Bh[n * PHB + ph];
    int  hs     = hh & 0xffff;
    int  he     = hh >> 16;

    int t      = threadIdx.x;
    int lane_w = t & 31;
    int cslot  = t >> 5;               // 0..7
    int wp4    = lane_w * 4;

    const int plane_stride = Hc * Wc;  // 32768

    // ---- Phase 1: rowmax -> LDS (float4 loads, 8 channels/thread) ----
    if (he > hs && wp4 < wwid) {
        const float* plane =
            feats + (size_t)(rb * Cc + c0 + cslot) * plane_stride;
        float4 rm[8];
#pragma unroll
        for (int j = 0; j < 8; ++j)
            rm[j] = make_float4(-1e37f, -1e37f, -1e37f, -1e37f);
        for (int h = hs; h < he; h += 2) {
            int hb   = min(h + 1, he - 1);
            int offa = h  * Wc + wlo_al + wp4;   // 16B-aligned, in-row
            int offb = hb * Wc + wlo_al + wp4;
#pragma unroll
            for (int j = 0; j < 8; ++j) {
                const float* pj = plane + (size_t)(8 * j) * plane_stride;
                float4 va = *reinterpret_cast<const float4*>(pj + offa);
                float4 vb = *reinterpret_cast<const float4*>(pj + offb);
                rm[j] = max4(rm[j], max4(va, vb));
            }
        }
#pragma unroll
        for (int j = 0; j < 8; ++j)
            *reinterpret_cast<float4*>(&smax[(cslot + 8 * j) * WST + wp4]) = rm[j];
    }
    __syncthreads();

    // ---- Phase 2: colmax from LDS, store ----
    int cv = Cw[n * PWB + lane_w];
    int ws = cv & 0x7fff;
    int we = ((unsigned)cv) >> 16;
    bool zero = (cv & 0x8000) || (he <= hs);

    size_t obase = ((size_t)(n * Cc + c0 + cslot) * PHB + ph) * PWB + lane_w;
    if (zero) {
#pragma unroll
        for (int j = 0; j < 8; ++j)
            out[obase + (size_t)(8 * j) * (PHB * PWB)] = 0.0f;
    } else {
#pragma unroll
        for (int j = 0; j < 8; ++j) {
            int cl = cslot + 8 * j;
            float m = -1e37f;
            for (int w = ws; w < we; ++w)
                m = fmaxf(m, smax[cl * WST + (w - wlo_al)]);
            out[obase + (size_t)(8 * j) * (PHB * PWB)] = m;
        }
    }
}

extern "C" void kernel_launch(void* const* d_in, const int* in_sizes, int n_in,
                              void* d_out, int out_size, void* d_ws, size_t ws_size,
                              hipStream_t stream) {
    const float* feats = (const float*)d_in[0];
    const float* rois  = (const float*)d_in[1];
    float* out = (float*)d_out;

    const int Cc = 128, Hc = 64, Wc = 512;
    int nroi = in_sizes[1] / 5;

    char* ws = (char*)d_ws;
    int4* A  = (int4*)(ws);
    int*  Bh = (int*) (ws + 4096);
    int*  Cw = (int*) (ws + 12288);

    roi_prep<<<(nroi + 63) / 64, 64, 0, stream>>>(rois, nroi, A, Bh, Cw, Hc, Wc);

    int blocks = nroi * PHB * (Cc / CHB);   // 4096
    ocr_roi_pool_kernel<<<blocks, BLK, 0, stream>>>(feats, A, Bh, Cw, out, Cc, Hc, Wc);
}

// Round 8
// 41.834 us; speedup vs baseline: 1.1884x; 1.1884x over previous
//
#include <hip/hip_runtime.h>

// ROI max-pool (aspect-preserving "OCR" variant) — separable two-phase, v5.
// feats: (B=4, C=128, H=64, W=512) fp32
// rois:  (N=256, 5) fp32 = [batch, x1, y1, x2, y2], spatial scale 0.25
// out:   (N, C, PH=8, PW=32) fp32
//
// Kernel 1 (roi_prep): per-ROI bin geometry -> d_ws (exact reference math).
// Kernel 2 (pool): grid (nroi, 32) 2D — x-fastest dispatch round-robins ROIs
// so co-resident blocks have mixed ROI sizes (load balance). Block = 256 thr
// = 32 w-lanes x 8 cslots, cslot covers 4 channels (stride 8); CHB=32 keeps
// LDS at 14.5 KB -> wave-capped occupancy (8 blocks/CU).
// Phase 1: rowmax over h -> LDS (float4). Phase 2: w-max from LDS.

#define PHB 8
#define PWB 32
#define CHB 32
#define WST 116         // >= max staged width (<=111)
#define BLK 256

static __device__ __forceinline__ float4 max4(float4 a, float4 b) {
    float4 r;
    r.x = fmaxf(a.x, b.x); r.y = fmaxf(a.y, b.y);
    r.z = fmaxf(a.z, b.z); r.w = fmaxf(a.w, b.w);
    return r;
}

// d_ws layout: A: int4[nroi] @0 ; Bh: int[nroi*8] @4096 ; Cw: int[nroi*32] @12288
__global__ void roi_prep(const float* __restrict__ rois, int nroi,
                         int4* __restrict__ A, int* __restrict__ Bh,
                         int* __restrict__ Cw, int Hc, int Wc)
{
#pragma clang fp contract(off)
    int i = blockIdx.x * 64 + threadIdx.x;
    if (i >= nroi) return;
    const float* r = rois + i * 5;
    int rb  = (int)r[0];
    int rsw = (int)floorf(r[1] * 0.25f + 0.5f);
    int rsh = (int)floorf(r[2] * 0.25f + 0.5f);
    int rew = (int)floorf(r[3] * 0.25f + 0.5f);
    int reh = (int)floorf(r[4] * 0.25f + 0.5f);

    int roi_w = max(rew - rsw + 1, 1);
    int roi_h = max(reh - rsh + 1, 1);
    int rpw   = (PHB * roi_w + roi_h - 1) / roi_h;

    float bsh = (float)roi_h / (float)PHB;
    float bsw = (float)roi_w / (float)rpw;

    // staged window (4-aligned); covers every non-pad bin's [ws,we)
    int wlo = min(max(rsw, 0), Wc);
    int whi = (int)ceilf((float)PWB * bsw) + rsw;
    whi = min(whi, rew + 4);
    whi = min(max(whi, 0), Wc);
    int wlo_al = wlo & ~3;
    int wwid   = min(whi - wlo_al, WST);

    A[i] = make_int4(rb, wlo_al, wwid, 0);

#pragma unroll
    for (int ph = 0; ph < PHB; ++ph) {
        int hs = (int)floorf((float)ph * bsh) + rsh;
        int he = (int)ceilf((float)(ph + 1) * bsh) + rsh;
        hs = min(max(hs, 0), Hc);
        he = min(max(he, 0), Hc);
        Bh[i * PHB + ph] = hs | (he << 16);
    }
#pragma unroll
    for (int pw = 0; pw < PWB; ++pw) {
        int ws = (int)floorf((float)pw * bsw) + rsw;
        int we = (int)ceilf((float)(pw + 1) * bsw) + rsw;
        ws = min(max(ws, 0), Wc);
        we = min(max(we, 0), Wc);
        int zw = (ws >= rew) || (we <= ws);   // pad or empty-in-w
        Cw[i * PWB + pw] = ws | (zw << 15) | (we << 16);
    }
}

__global__ __launch_bounds__(BLK) void ocr_roi_pool_kernel(
    const float* __restrict__ feats,
    const int4* __restrict__ A,
    const int* __restrict__ Bh,
    const int* __restrict__ Cw,
    float* __restrict__ out,
    int Cc, int Hc, int Wc)
{
    __shared__ float smax[CHB * WST];

    int n  = blockIdx.x;               // roi (x-fastest -> round-robin ROIs)
    int s  = blockIdx.y;               // 0..31
    int ph = s >> 2;
    int cq = s & 3;
    int c0 = cq * CHB;

    int t      = threadIdx.x;
    int lane_w = t & 31;
    int cslot  = t >> 5;               // 0..7
    int wp4    = lane_w * 4;

    // geometry (A,Bh uniform -> s_load; Cw per-lane, issued early)
    int  cv     = Cw[n * PWB + lane_w];
    int4 a      = A[n];
    int  rb     = a.x;
    int  wlo_al = a.y;
    int  wwid   = a.z;
    int  hh     = Bh[n * PHB + ph];
    int  hs     = hh & 0xffff;
    int  he     = hh >> 16;

    const int plane_stride = Hc * Wc;  // 32768

    // ---- Phase 1: rowmax -> LDS (float4 loads, 4 channels/thread) ----
    if (he > hs && wp4 < wwid) {
        const float* plane =
            feats + (size_t)(rb * Cc + c0 + cslot) * plane_stride;
        float4 rm[4];
#pragma unroll
        for (int j = 0; j < 4; ++j)
            rm[j] = make_float4(-1e37f, -1e37f, -1e37f, -1e37f);
        for (int h = hs; h < he; h += 2) {
            int hb   = min(h + 1, he - 1);
            int offa = h  * Wc + wlo_al + wp4;   // 16B-aligned, in-row
            int offb = hb * Wc + wlo_al + wp4;
#pragma unroll
            for (int j = 0; j < 4; ++j) {
                const float* pj = plane + (size_t)(8 * j) * plane_stride;
                float4 va = *reinterpret_cast<const float4*>(pj + offa);
                float4 vb = *reinterpret_cast<const float4*>(pj + offb);
                rm[j] = max4(rm[j], max4(va, vb));
            }
        }
#pragma unroll
        for (int j = 0; j < 4; ++j)
            *reinterpret_cast<float4*>(&smax[(cslot + 8 * j) * WST + wp4]) = rm[j];
    }
    __syncthreads();

    // ---- Phase 2: colmax from LDS, store ----
    int ws = cv & 0x7fff;
    int we = ((unsigned)cv) >> 16;
    bool zero = (cv & 0x8000) || (he <= hs);

    size_t obase = ((size_t)(n * Cc + c0 + cslot) * PHB + ph) * PWB + lane_w;
    if (zero) {
#pragma unroll
        for (int j = 0; j < 4; ++j)
            out[obase + (size_t)(8 * j) * (PHB * PWB)] = 0.0f;
    } else {
#pragma unroll
        for (int j = 0; j < 4; ++j) {
            int cl = cslot + 8 * j;
            float m = -1e37f;
            for (int w = ws; w < we; ++w)
                m = fmaxf(m, smax[cl * WST + (w - wlo_al)]);
            out[obase + (size_t)(8 * j) * (PHB * PWB)] = m;
        }
    }
}

extern "C" void kernel_launch(void* const* d_in, const int* in_sizes, int n_in,
                              void* d_out, int out_size, void* d_ws, size_t ws_size,
                              hipStream_t stream) {
    const float* feats = (const float*)d_in[0];
    const float* rois  = (const float*)d_in[1];
    float* out = (float*)d_out;

    const int Cc = 128, Hc = 64, Wc = 512;
    int nroi = in_sizes[1] / 5;

    char* ws = (char*)d_ws;
    int4* A  = (int4*)(ws);
    int*  Bh = (int*) (ws + 4096);
    int*  Cw = (int*) (ws + 12288);

    roi_prep<<<(nroi + 63) / 64, 64, 0, stream>>>(rois, nroi, A, Bh, Cw, Hc, Wc);

    dim3 grid(nroi, PHB * (Cc / CHB));   // (256, 32): x-fastest = ROI round-robin
    ocr_roi_pool_kernel<<<grid, BLK, 0, stream>>>(feats, A, Bh, Cw, out, Cc, Hc, Wc);
}

// Round 9
// 33.374 us; speedup vs baseline: 1.4897x; 1.2535x over previous
//
#include <hip/hip_runtime.h>

// ROI max-pool (aspect-preserving "OCR" variant) — separable two-phase, v6.
// feats: (B=4, C=128, H=64, W=512) fp32
// rois:  (N, 5) fp32 = [batch, x1, y1, x2, y2] image coords, spatial scale 0.25
// out:   (N, C, PH=8, PW=32) fp32
//
// Single kernel (R5 base — prep kernel was a net loss). Block = (roi, ph,
// channel-quarter of 32). 256 thr = 32 w-lanes x 8 cslots, cslot covers 4
// channels (stride 8). Phase 1: rowmax over h -> LDS via float4 loads on a
// 4-aligned window. Phase 2: w-max from LDS as a FIXED 8-wide masked unroll
// (bin width <= 5 since bsw <= 3.375): 8 independent ds_read_b32 pipelined
// in one latency window instead of a ~14-deep loop-carried LDS chain.

#define PHB 8
#define PWB 32
#define CHB 32          // channels per block
#define WST 116         // staged width cap: ceil(32*bsw) <= 108, +3 align
#define BLK 256

static __device__ __forceinline__ float4 max4(float4 a, float4 b) {
    float4 r;
    r.x = fmaxf(a.x, b.x); r.y = fmaxf(a.y, b.y);
    r.z = fmaxf(a.z, b.z); r.w = fmaxf(a.w, b.w);
    return r;
}

__global__ __launch_bounds__(BLK) void ocr_roi_pool_kernel(
    const float* __restrict__ feats,
    const float* __restrict__ rois,
    float* __restrict__ out,
    int Cc, int Hc, int Wc)
{
#pragma clang fp contract(off)
    __shared__ float smax[CHB * WST + 8];   // +8: phase-2 unroll over-read pad

    int b  = blockIdx.x;               // ((n*8 + ph)*4 + cq)
    int cq = b & 3;
    int ph = (b >> 2) & 7;
    int n  = b >> 5;
    int c0 = cq * CHB;

    // ---- ROI params: block-uniform -> scalar ----
    const float* r = rois + n * 5;
    int rb  = (int)r[0];
    int rsw = (int)floorf(r[1] * 0.25f + 0.5f);
    int rsh = (int)floorf(r[2] * 0.25f + 0.5f);
    int rew = (int)floorf(r[3] * 0.25f + 0.5f);
    int reh = (int)floorf(r[4] * 0.25f + 0.5f);

    int roi_w = max(rew - rsw + 1, 1);
    int roi_h = max(reh - rsh + 1, 1);
    int rpw   = (PHB * roi_w + roi_h - 1) / roi_h;

    float bsh = (float)roi_h / (float)PHB;
    float bsw = (float)roi_w / (float)rpw;

    // h-range for this ph (uniform over block), exact reference math
    int hs = (int)floorf((float)ph * bsh) + rsh;
    int he = (int)ceilf((float)(ph + 1) * bsh) + rsh;
    hs = min(max(hs, 0), Hc);
    he = min(max(he, 0), Hc);

    // staged w-window: covers every NON-PAD bin's reads; 4-aligned base.
    int wlo = min(max(rsw, 0), Wc);
    int whi = (int)ceilf((float)PWB * bsw) + rsw;
    whi = min(whi, rew + 4);
    whi = min(max(whi, 0), Wc);
    int wlo_al = wlo & ~3;
    int wwid = min(whi - wlo_al, WST);

    int t      = threadIdx.x;
    int lane_w = t & 31;
    int cslot  = t >> 5;               // 0..7
    int wp4    = lane_w * 4;           // this lane's 4-column slot

    const int plane_stride = Hc * Wc;  // 32768

    // ---- Phase 1: rowmax -> LDS (float4 loads, h unrolled x2) ----
    if (he > hs && wp4 < wwid) {
        const float* plane =
            feats + ((size_t)(rb * Cc + c0 + cslot) * Hc) * Wc;
        float4 rm[4];
#pragma unroll
        for (int j = 0; j < 4; ++j)
            rm[j] = make_float4(-1e37f, -1e37f, -1e37f, -1e37f);
        for (int h = hs; h < he; h += 2) {
            int hb   = min(h + 1, he - 1);
            int offa = h  * Wc + wlo_al + wp4;   // 16B-aligned, in-row
            int offb = hb * Wc + wlo_al + wp4;
#pragma unroll
            for (int j = 0; j < 4; ++j) {
                const float* pj = plane + (size_t)(8 * j) * plane_stride;
                float4 va = *reinterpret_cast<const float4*>(pj + offa);
                float4 vb = *reinterpret_cast<const float4*>(pj + offb);
                rm[j] = max4(rm[j], max4(va, vb));
            }
        }
#pragma unroll
        for (int j = 0; j < 4; ++j)   // 464B row stride: 16B-aligned
            *reinterpret_cast<float4*>(&smax[(cslot + 8 * j) * WST + wp4]) = rm[j];
    }
    __syncthreads();

    // ---- Phase 2: colmax from LDS (fixed 8-wide masked unroll), store ----
    int pw = lane_w;
    int ws = (int)floorf((float)pw * bsw) + rsw;
    int we = (int)ceilf((float)(pw + 1) * bsw) + rsw;
    ws = min(max(ws, 0), Wc);
    we = min(max(we, 0), Wc);

    bool pad   = (ws >= rew);
    bool empty = (he <= hs) || (we <= ws);

    size_t obase = (((size_t)n * Cc + c0 + cslot) * PHB + ph) * PWB + pw;
    if (pad || empty) {
#pragma unroll
        for (int j = 0; j < 4; ++j)
            out[obase + (size_t)(8 * j) * (PHB * PWB)] = 0.0f;
    } else {
        int base = ws - wlo_al;        // >= 0
        int nw   = we - ws;            // 1..5 (bsw <= 3.375)
#pragma unroll
        for (int j = 0; j < 4; ++j) {
            const float* row = &smax[(cslot + 8 * j) * WST + base];
            float m = -1e37f;
#pragma unroll
            for (int i = 0; i < 8; ++i) {        // 8 independent ds_reads,
                float v = row[i];                // masked beyond nw
                m = (i < nw) ? fmaxf(m, v) : m;
            }
            out[obase + (size_t)(8 * j) * (PHB * PWB)] = m;
        }
    }
}

extern "C" void kernel_launch(void* const* d_in, const int* in_sizes, int n_in,
                              void* d_out, int out_size, void* d_ws, size_t ws_size,
                              hipStream_t stream) {
    const float* feats = (const float*)d_in[0];
    const float* rois  = (const float*)d_in[1];
    float* out = (float*)d_out;

    const int Cc = 128, Hc = 64, Wc = 512;
    int nroi = in_sizes[1] / 5;
    int blocks = nroi * PHB * (Cc / CHB);   // 8192

    ocr_roi_pool_kernel<<<blocks, BLK, 0, stream>>>(feats, rois, out, Cc, Hc, Wc);
}

// Round 10
// 26.898 us; speedup vs baseline: 1.8483x; 1.2408x over previous
//
#include <hip/hip_runtime.h>

// ROI max-pool (aspect-preserving "OCR" variant) — separable two-phase, v7.
// feats: (B=4, C=128, H=64, W=512) fp32
// rois:  (N, 5) fp32 = [batch, x1, y1, x2, y2] image coords, spatial scale 0.25
// out:   (N, C, PH=8, PW=32) fp32
//
// Single kernel. Block = 128 threads (2 waves) = 32 w-lanes x 4 cslots, one
// (roi, ph, channel-group of 16); cslot covers 4 channels (stride 4).
// 16384 blocks -> 16 blocks/CU residency slots: finer scheduling granularity
// over the ~10x ROI-size spread (R8's 60% occupancy was tail/imbalance).
// Phase 1: rowmax over h -> LDS via float4 loads on a 4-aligned window.
// Phase 2: w-max from LDS as a fixed 8-wide masked unroll (bin width <= 5).

#define PHB 8
#define PWB 32
#define CHB 16          // channels per block
#define WST 116         // staged width cap: ceil(32*bsw) <= 108, +3 align
#define BLK 128

static __device__ __forceinline__ float4 max4(float4 a, float4 b) {
    float4 r;
    r.x = fmaxf(a.x, b.x); r.y = fmaxf(a.y, b.y);
    r.z = fmaxf(a.z, b.z); r.w = fmaxf(a.w, b.w);
    return r;
}

__global__ __launch_bounds__(BLK) void ocr_roi_pool_kernel(
    const float* __restrict__ feats,
    const float* __restrict__ rois,
    float* __restrict__ out,
    int Cc, int Hc, int Wc)
{
#pragma clang fp contract(off)
    __shared__ float smax[CHB * WST + 8];   // +8: phase-2 unroll over-read pad

    int b  = blockIdx.x;               // ((n*8 + ph)*8 + cg)
    int cg = b & 7;
    int ph = (b >> 3) & 7;
    int n  = b >> 6;
    int c0 = cg * CHB;

    // ---- ROI params: block-uniform -> scalar ----
    const float* r = rois + n * 5;
    int rb  = (int)r[0];
    int rsw = (int)floorf(r[1] * 0.25f + 0.5f);
    int rsh = (int)floorf(r[2] * 0.25f + 0.5f);
    int rew = (int)floorf(r[3] * 0.25f + 0.5f);
    int reh = (int)floorf(r[4] * 0.25f + 0.5f);

    int roi_w = max(rew - rsw + 1, 1);
    int roi_h = max(reh - rsh + 1, 1);
    int rpw   = (PHB * roi_w + roi_h - 1) / roi_h;

    float bsh = (float)roi_h / (float)PHB;
    float bsw = (float)roi_w / (float)rpw;

    // h-range for this ph (uniform over block), exact reference math
    int hs = (int)floorf((float)ph * bsh) + rsh;
    int he = (int)ceilf((float)(ph + 1) * bsh) + rsh;
    hs = min(max(hs, 0), Hc);
    he = min(max(he, 0), Hc);

    // staged w-window: covers every NON-PAD bin's reads; 4-aligned base.
    int wlo = min(max(rsw, 0), Wc);
    int whi = (int)ceilf((float)PWB * bsw) + rsw;
    whi = min(whi, rew + 4);
    whi = min(max(whi, 0), Wc);
    int wlo_al = wlo & ~3;
    int wwid = min(whi - wlo_al, WST);

    int t      = threadIdx.x;
    int lane_w = t & 31;
    int cslot  = t >> 5;               // 0..3
    int wp4    = lane_w * 4;           // this lane's 4-column slot

    const int plane_stride = Hc * Wc;  // 32768

    // ---- Phase 1: rowmax -> LDS (float4 loads, h unrolled x2) ----
    if (he > hs && wp4 < wwid) {
        const float* plane =
            feats + ((size_t)(rb * Cc + c0 + cslot) * Hc) * Wc;
        float4 rm[4];
#pragma unroll
        for (int j = 0; j < 4; ++j)
            rm[j] = make_float4(-1e37f, -1e37f, -1e37f, -1e37f);
        for (int h = hs; h < he; h += 2) {
            int hb   = min(h + 1, he - 1);
            int offa = h  * Wc + wlo_al + wp4;   // 16B-aligned, in-row
            int offb = hb * Wc + wlo_al + wp4;
#pragma unroll
            for (int j = 0; j < 4; ++j) {
                const float* pj = plane + (size_t)(4 * j) * plane_stride;
                float4 va = *reinterpret_cast<const float4*>(pj + offa);
                float4 vb = *reinterpret_cast<const float4*>(pj + offb);
                rm[j] = max4(rm[j], max4(va, vb));
            }
        }
#pragma unroll
        for (int j = 0; j < 4; ++j)   // 464B row stride: 16B-aligned
            *reinterpret_cast<float4*>(&smax[(cslot + 4 * j) * WST + wp4]) = rm[j];
    }
    __syncthreads();

    // ---- Phase 2: colmax from LDS (fixed 8-wide masked unroll), store ----
    int pw = lane_w;
    int ws = (int)floorf((float)pw * bsw) + rsw;
    int we = (int)ceilf((float)(pw + 1) * bsw) + rsw;
    ws = min(max(ws, 0), Wc);
    we = min(max(we, 0), Wc);

    bool pad   = (ws >= rew);
    bool empty = (he <= hs) || (we <= ws);

    size_t obase = (((size_t)n * Cc + c0 + cslot) * PHB + ph) * PWB + pw;
    if (pad || empty) {
#pragma unroll
        for (int j = 0; j < 4; ++j)
            out[obase + (size_t)(4 * j) * (PHB * PWB)] = 0.0f;
    } else {
        int base = ws - wlo_al;        // >= 0
        int nw   = we - ws;            // 1..5 (bsw <= 3.375)
#pragma unroll
        for (int j = 0; j < 4; ++j) {
            const float* row = &smax[(cslot + 4 * j) * WST + base];
            float m = -1e37f;
#pragma unroll
            for (int i = 0; i < 8; ++i) {        // 8 independent ds_reads,
                float v = row[i];                // masked beyond nw
                m = (i < nw) ? fmaxf(m, v) : m;
            }
            out[obase + (size_t)(4 * j) * (PHB * PWB)] = m;
        }
    }
}

extern "C" void kernel_launch(void* const* d_in, const int* in_sizes, int n_in,
                              void* d_out, int out_size, void* d_ws, size_t ws_size,
                              hipStream_t stream) {
    const float* feats = (const float*)d_in[0];
    const float* rois  = (const float*)d_in[1];
    float* out = (float*)d_out;

    const int Cc = 128, Hc = 64, Wc = 512;
    int nroi = in_sizes[1] / 5;
    int blocks = nroi * PHB * (Cc / CHB);   // 16384

    ocr_roi_pool_kernel<<<blocks, BLK, 0, stream>>>(feats, rois, out, Cc, Hc, Wc);
}

// Round 11
// 25.828 us; speedup vs baseline: 1.9248x; 1.0414x over previous
//
#include <hip/hip_runtime.h>

// ROI max-pool (aspect-preserving "OCR" variant) — separable two-phase, v8.
// feats: (B=4, C=128, H=64, W=512) fp32
// rois:  (N, 5) fp32 = [batch, x1, y1, x2, y2] image coords, spatial scale 0.25
// out:   (N, C, PH=8, PW=32) fp32
//
// Single kernel. Block = 64 threads (1 wave) = 32 w-lanes x 2 cslots, one
// (roi, ph, channel-group of 8); cslot covers 4 channels (stride 2).
// 32768 blocks -> 32 single-wave blocks/CU: finest scheduling granularity
// over the ~10x ROI-size spread (R9: 128-thr blocks took 33.4 -> 26.9 us).
// Phase 1: rowmax over h -> LDS via float4 loads on a 4-aligned window.
// Phase 2: w-max from LDS as a fixed 8-wide masked unroll (bin width <= 5).

#define PHB 8
#define PWB 32
#define CHB 8           // channels per block
#define WST 116         // staged width cap: ceil(32*bsw) <= 108, +3 align
#define BLK 64

static __device__ __forceinline__ float4 max4(float4 a, float4 b) {
    float4 r;
    r.x = fmaxf(a.x, b.x); r.y = fmaxf(a.y, b.y);
    r.z = fmaxf(a.z, b.z); r.w = fmaxf(a.w, b.w);
    return r;
}

__global__ __launch_bounds__(BLK) void ocr_roi_pool_kernel(
    const float* __restrict__ feats,
    const float* __restrict__ rois,
    float* __restrict__ out,
    int Cc, int Hc, int Wc)
{
#pragma clang fp contract(off)
    __shared__ float smax[CHB * WST + 8];   // +8: phase-2 unroll over-read pad

    int b  = blockIdx.x;               // ((n*8 + ph)*16 + cg)
    int cg = b & 15;
    int ph = (b >> 4) & 7;
    int n  = b >> 7;
    int c0 = cg * CHB;

    // ---- ROI params: block-uniform -> scalar ----
    const float* r = rois + n * 5;
    int rb  = (int)r[0];
    int rsw = (int)floorf(r[1] * 0.25f + 0.5f);
    int rsh = (int)floorf(r[2] * 0.25f + 0.5f);
    int rew = (int)floorf(r[3] * 0.25f + 0.5f);
    int reh = (int)floorf(r[4] * 0.25f + 0.5f);

    int roi_w = max(rew - rsw + 1, 1);
    int roi_h = max(reh - rsh + 1, 1);
    int rpw   = (PHB * roi_w + roi_h - 1) / roi_h;

    float bsh = (float)roi_h / (float)PHB;
    float bsw = (float)roi_w / (float)rpw;

    // h-range for this ph (uniform over block), exact reference math
    int hs = (int)floorf((float)ph * bsh) + rsh;
    int he = (int)ceilf((float)(ph + 1) * bsh) + rsh;
    hs = min(max(hs, 0), Hc);
    he = min(max(he, 0), Hc);

    // staged w-window: covers every NON-PAD bin's reads; 4-aligned base.
    int wlo = min(max(rsw, 0), Wc);
    int whi = (int)ceilf((float)PWB * bsw) + rsw;
    whi = min(whi, rew + 4);
    whi = min(max(whi, 0), Wc);
    int wlo_al = wlo & ~3;
    int wwid = min(whi - wlo_al, WST);

    int t      = threadIdx.x;
    int lane_w = t & 31;
    int cslot  = t >> 5;               // 0..1
    int wp4    = lane_w * 4;           // this lane's 4-column slot

    const int plane_stride = Hc * Wc;  // 32768

    // ---- Phase 1: rowmax -> LDS (float4 loads, h unrolled x2) ----
    if (he > hs && wp4 < wwid) {
        const float* plane =
            feats + ((size_t)(rb * Cc + c0 + cslot) * Hc) * Wc;
        float4 rm[4];
#pragma unroll
        for (int j = 0; j < 4; ++j)
            rm[j] = make_float4(-1e37f, -1e37f, -1e37f, -1e37f);
        for (int h = hs; h < he; h += 2) {
            int hb   = min(h + 1, he - 1);
            int offa = h  * Wc + wlo_al + wp4;   // 16B-aligned, in-row
            int offb = hb * Wc + wlo_al + wp4;
#pragma unroll
            for (int j = 0; j < 4; ++j) {
                const float* pj = plane + (size_t)(2 * j) * plane_stride;
                float4 va = *reinterpret_cast<const float4*>(pj + offa);
                float4 vb = *reinterpret_cast<const float4*>(pj + offb);
                rm[j] = max4(rm[j], max4(va, vb));
            }
        }
#pragma unroll
        for (int j = 0; j < 4; ++j)   // 464B row stride: 16B-aligned
            *reinterpret_cast<float4*>(&smax[(cslot + 2 * j) * WST + wp4]) = rm[j];
    }
    __syncthreads();

    // ---- Phase 2: colmax from LDS (fixed 8-wide masked unroll), store ----
    int pw = lane_w;
    int ws = (int)floorf((float)pw * bsw) + rsw;
    int we = (int)ceilf((float)(pw + 1) * bsw) + rsw;
    ws = min(max(ws, 0), Wc);
    we = min(max(we, 0), Wc);

    bool pad   = (ws >= rew);
    bool empty = (he <= hs) || (we <= ws);

    size_t obase = (((size_t)n * Cc + c0 + cslot) * PHB + ph) * PWB + pw;
    if (pad || empty) {
#pragma unroll
        for (int j = 0; j < 4; ++j)
            out[obase + (size_t)(2 * j) * (PHB * PWB)] = 0.0f;
    } else {
        int base = ws - wlo_al;        // >= 0
        int nw   = we - ws;            // 1..5 (bsw <= 3.375)
#pragma unroll
        for (int j = 0; j < 4; ++j) {
            const float* row = &smax[(cslot + 2 * j) * WST + base];
            float m = -1e37f;
#pragma unroll
            for (int i = 0; i < 8; ++i) {        // 8 independent ds_reads,
                float v = row[i];                // masked beyond nw
                m = (i < nw) ? fmaxf(m, v) : m;
            }
            out[obase + (size_t)(2 * j) * (PHB * PWB)] = m;
        }
    }
}

extern "C" void kernel_launch(void* const* d_in, const int* in_sizes, int n_in,
                              void* d_out, int out_size, void* d_ws, size_t ws_size,
                              hipStream_t stream) {
    const float* feats = (const float*)d_in[0];
    const float* rois  = (const float*)d_in[1];
    float* out = (float*)d_out;

    const int Cc = 128, Hc = 64, Wc = 512;
    int nroi = in_sizes[1] / 5;
    int blocks = nroi * PHB * (Cc / CHB);   // 32768

    ocr_roi_pool_kernel<<<blocks, BLK, 0, stream>>>(feats, rois, out, Cc, Hc, Wc);
}